// Round 4
// baseline (257.965 us; speedup 1.0000x reference)
//
#include <hip/hip_runtime.h>

typedef _Float16 f16;
typedef __attribute__((ext_vector_type(8))) _Float16 half8;
typedef __attribute__((ext_vector_type(4))) _Float16 half4;
typedef __attribute__((ext_vector_type(4))) float f32x4;

#define LDS_AS __attribute__((address_space(3)))
#define GLB_AS __attribute__((address_space(1)))

__device__ __forceinline__ void load16_lds(const f16* g, f16* l) {
    __builtin_amdgcn_global_load_lds((GLB_AS void*)(g), (LDS_AS void*)(l), 16, 0, 0);
}

// stage s+1 in flight while computing stage s; wait only for stage s's 4 loads
#define WAIT4_BARRIER()  asm volatile("s_waitcnt vmcnt(4)\n\ts_barrier" ::: "memory")
#define WAIT0_BARRIER()  asm volatile("s_waitcnt vmcnt(0)\n\ts_barrier" ::: "memory")
#define PLAIN_BARRIER()  asm volatile("s_barrier" ::: "memory")

// ---------------------------------------------------------------------------
// GEMM1: h_t[2048][11520] = W1t[2048][512] @ xh[11520][512]^T + b1(row), f16
// 2-stage pipelined K-loop; XCD swizzle (each xh n-column owned by one XCD).
// ---------------------------------------------------------------------------
__global__ __launch_bounds__(256, 2) void gemm1(
    const f16* __restrict__ A, const f16* __restrict__ Bt,
    const float* __restrict__ bias, f16* __restrict__ C)
{
    const int id  = blockIdx.x;
    const int xcd = id & 7;
    const int r   = id >> 3;
    const int mt  = r & 15;
    const int nt  = xcd + 8 * (r >> 4);
    if (nt >= 90) return;
    const int m0 = mt * 128, n0 = nt * 128;
    const int K = 512, ldc = 11520;

    __shared__ f16 As[2][128 * 32];
    __shared__ f16 Bs[2][128 * 32];
    const int tid  = threadIdx.x;
    const int wave = tid >> 6;
    const int lane = tid & 63;

    const int s0 = tid, s1 = tid + 256;
    const f16* gA0 = A  + (m0 + (s0 >> 2)) * K + (s0 & 3) * 8;
    const f16* gA1 = A  + (m0 + (s1 >> 2)) * K + (s1 & 3) * 8;
    const f16* gB0 = Bt + (n0 + (s0 >> 2)) * K + (s0 & 3) * 8;
    const f16* gB1 = Bt + (n0 + (s1 >> 2)) * K + (s1 & 3) * 8;

    const int wm = (wave >> 1) * 64;
    const int wn = (wave & 1) * 64;
    const int lr = lane & 15;
    const int k8 = (lane >> 4) * 8;

    f32x4 acc[4][4];
#pragma unroll
    for (int i = 0; i < 4; ++i)
#pragma unroll
        for (int j = 0; j < 4; ++j) acc[i][j] = f32x4{0.f, 0.f, 0.f, 0.f};

#define G1_ISSUE(st, k0) do { \
    load16_lds(gA0 + (k0), &As[st][wave * 512]); \
    load16_lds(gA1 + (k0), &As[st][2048 + wave * 512]); \
    load16_lds(gB0 + (k0), &Bs[st][wave * 512]); \
    load16_lds(gB1 + (k0), &Bs[st][2048 + wave * 512]); \
} while (0)

    G1_ISSUE(0, 0);
    const int NS = 16;                 // 512 / 32
    for (int s = 0; s < NS; ++s) {
        const int cur = s & 1;
        if (s + 1 < NS) {
            G1_ISSUE(cur ^ 1, (s + 1) * 32);
            WAIT4_BARRIER();
        } else {
            WAIT0_BARRIER();
        }
        half8 af[4], bf[4];
#pragma unroll
        for (int i = 0; i < 4; ++i)
            af[i] = *(const half8*)&As[cur][(wm + i * 16 + lr) * 32 + k8];
#pragma unroll
        for (int j = 0; j < 4; ++j)
            bf[j] = *(const half8*)&Bs[cur][(wn + j * 16 + lr) * 32 + k8];
#pragma unroll
        for (int i = 0; i < 4; ++i)
#pragma unroll
            for (int j = 0; j < 4; ++j)
                acc[i][j] = __builtin_amdgcn_mfma_f32_16x16x32_f16(
                    af[i], bf[j], acc[i][j], 0, 0, 0);
        PLAIN_BARRIER();               // no drain: protects stage reuse only
    }

#pragma unroll
    for (int i = 0; i < 4; ++i) {
#pragma unroll
        for (int rr = 0; rr < 4; ++rr) {
            const int row = m0 + wm + i * 16 + (lane >> 4) * 4 + rr;
            const float bvr = (row < 1960) ? bias[row] : 0.f;
#pragma unroll
            for (int j = 0; j < 4; ++j) {
                const int col = n0 + wn + j * 16 + lr;
                C[row * ldc + col] = (f16)(acc[i][j][rr] + bvr);
            }
        }
    }
}

// ---------------------------------------------------------------------------
// GEMM2: out[11520][512] += g16[11520][2048] @ W2t[512][2048]^T  (f32 atomics)
// split-K=2 (720 active blocks), 2-stage pipeline, XCD swizzle. Bias comes
// from bias_fill which pre-writes out = b2.
// ---------------------------------------------------------------------------
__global__ __launch_bounds__(256, 2) void gemm2(
    const f16* __restrict__ A, const f16* __restrict__ Bt,
    float* __restrict__ Cout)
{
    const int id  = blockIdx.x;
    const int xcd = id & 7;
    const int r   = id >> 3;           // 0..95
    const int kh  = r & 1;
    const int rr_ = r >> 1;            // 0..47
    const int nt  = rr_ & 3;
    const int mt  = (rr_ >> 2) * 8 + xcd;
    if (mt >= 90) return;
    const int m0 = mt * 128, n0 = nt * 128;

    __shared__ f16 As[2][128 * 32];
    __shared__ f16 Bs[2][128 * 32];
    const int tid  = threadIdx.x;
    const int wave = tid >> 6;
    const int lane = tid & 63;

    const int s0 = tid, s1 = tid + 256;
    const int kbase = kh * 1024;
    const f16* gA0 = A  + (m0 + (s0 >> 2)) * 2048 + kbase + (s0 & 3) * 8;
    const f16* gA1 = A  + (m0 + (s1 >> 2)) * 2048 + kbase + (s1 & 3) * 8;
    const f16* gB0 = Bt + (n0 + (s0 >> 2)) * 2048 + kbase + (s0 & 3) * 8;
    const f16* gB1 = Bt + (n0 + (s1 >> 2)) * 2048 + kbase + (s1 & 3) * 8;

    const int wm = (wave >> 1) * 64;
    const int wn = (wave & 1) * 64;
    const int lr = lane & 15;
    const int k8 = (lane >> 4) * 8;

    f32x4 acc[4][4];
#pragma unroll
    for (int i = 0; i < 4; ++i)
#pragma unroll
        for (int j = 0; j < 4; ++j) acc[i][j] = f32x4{0.f, 0.f, 0.f, 0.f};

#define G2_ISSUE(st, k0) do { \
    load16_lds(gA0 + (k0), &As[st][wave * 512]); \
    load16_lds(gA1 + (k0), &As[st][2048 + wave * 512]); \
    load16_lds(gB0 + (k0), &Bs[st][wave * 512]); \
    load16_lds(gB1 + (k0), &Bs[st][2048 + wave * 512]); \
} while (0)

    G2_ISSUE(0, 0);
    const int NS = 32;                 // 1024 / 32
    for (int s = 0; s < NS; ++s) {
        const int cur = s & 1;
        if (s + 1 < NS) {
            G2_ISSUE(cur ^ 1, (s + 1) * 32);
            WAIT4_BARRIER();
        } else {
            WAIT0_BARRIER();
        }
        half8 af[4], bf[4];
#pragma unroll
        for (int i = 0; i < 4; ++i)
            af[i] = *(const half8*)&As[cur][(wm + i * 16 + lr) * 32 + k8];
#pragma unroll
        for (int j = 0; j < 4; ++j)
            bf[j] = *(const half8*)&Bs[cur][(wn + j * 16 + lr) * 32 + k8];
#pragma unroll
        for (int i = 0; i < 4; ++i)
#pragma unroll
            for (int j = 0; j < 4; ++j)
                acc[i][j] = __builtin_amdgcn_mfma_f32_16x16x32_f16(
                    af[i], bf[j], acc[i][j], 0, 0, 0);
        PLAIN_BARRIER();
    }

#pragma unroll
    for (int j = 0; j < 4; ++j) {
        const int col = n0 + wn + j * 16 + lr;
#pragma unroll
        for (int i = 0; i < 4; ++i) {
            const int rbase = m0 + wm + i * 16 + (lane >> 4) * 4;
#pragma unroll
            for (int q = 0; q < 4; ++q)
                atomicAdd(&Cout[(rbase + q) * 512 + col], acc[i][j][q]);
        }
    }
}

// out[t][c] = b2[c]  (pre-fill so gemm2 halves can pure-accumulate)
__global__ void bias_fill(const float* __restrict__ b2, float* __restrict__ out)
{
    const int i = blockIdx.x * 256 + threadIdx.x;   // < 1474560 float4s
    ((float4*)out)[i] = ((const float4*)b2)[i & 127];
}

// ---------------------------------------------------------------------------
// fold (gather form) + normalize + exact GELU, h_t[2048][11520] -> imgG f16
// ---------------------------------------------------------------------------
__global__ void fold_gelu(const f16* __restrict__ h_t, f16* __restrict__ imgG)
{
    const int r  = blockIdx.x;        // 0..65
    const int bc = blockIdx.y;        // bp*40 + cch
    const int bp  = bc / 40;
    const int cch = bc % 40;
    const int c = threadIdx.x;
    if (c >= 114) return;
    float outv = 0.f;
    if (r >= 3 && r < 63 && c >= 3 && c < 111) {
        const int qr = r / 3, rm = r % 3;
        const int qc = c / 3, cm = c % 3;
        int kis[3], ohs[3], nr = 0;
        int kjs[3], ows[3], nc = 0;
#pragma unroll
        for (int t = 0; t < 3; ++t) {
            const int ki = rm + 3 * t, oh = qr - t;
            if (ki < 7 && oh >= 0 && oh < 20) { kis[nr] = ki; ohs[nr] = oh; ++nr; }
            const int kj = cm + 3 * t, ow = qc - t;
            if (kj < 7 && ow >= 0 && ow < 36) { kjs[nc] = kj; ows[nc] = ow; ++nc; }
        }
        float sum = 0.f;
        for (int a = 0; a < nr; ++a)
            for (int b = 0; b < nc; ++b) {
                const int n = cch * 49 + kis[a] * 7 + kjs[b];
                const int token = bp * 720 + ohs[a] * 36 + ows[b];
                sum += (float)h_t[n * 11520 + token];
            }
        const float xv = sum / (float)(nr * nc);
        outv = 0.5f * xv * (1.f + erff(xv * 0.70710678118654752f));
    }
    imgG[(bc * 66 + r) * 114 + c] = (f16)outv;
}

// ---------------------------------------------------------------------------
// unfold: stage one channel image (15 KB) in LDS, then gather + write g16.
// Block per (bp,cch); cch>=36 blocks also zero tail cols [1960,2048).
// ---------------------------------------------------------------------------
__global__ __launch_bounds__(256) void unfold_lds(
    const f16* __restrict__ imgG, f16* __restrict__ g16)
{
    __shared__ f16 ch[7524];
    const int bc = blockIdx.x;        // 0..639
    const int bp = bc / 40, cch = bc % 40;
    const float* src = (const float*)(imgG + bc * 7524);
    float* dst = (float*)ch;
    for (int i = threadIdx.x; i < 3762; i += 256) dst[i] = src[i];
    __syncthreads();
    const int tokbase = bp * 720;
    const int colbase = cch * 49;
    for (int flat = threadIdx.x; flat < 35280; flat += 256) {
        const int l = flat / 49, k = flat - l * 49;
        const int oh = l / 36, ow = l - oh * 36;
        const int ki = k / 7,  kj = k - ki * 7;
        g16[(tokbase + l) * 2048 + colbase + k] =
            ch[(oh * 3 + ki) * 114 + ow * 3 + kj];
    }
    if (cch >= 36) {
        const int cb = 1960 + (cch - 36) * 22;   // 4 blocks x 22 cols = 88
        for (int flat = threadIdx.x; flat < 720 * 22; flat += 256) {
            const int l = flat / 22, k = flat - l * 22;
            g16[(tokbase + l) * 2048 + cb + k] = (f16)0.f;
        }
    }
}

// ---------------------------------------------------------------------------
__global__ void cvt_x(const float* __restrict__ x, f16* __restrict__ xh, int n4)
{
    const int i = blockIdx.x * 256 + threadIdx.x;
    if (i < n4) {
        const float4 v = ((const float4*)x)[i];
        half4 o;
        o[0] = (f16)v.x; o[1] = (f16)v.y; o[2] = (f16)v.z; o[3] = (f16)v.w;
        ((half4*)xh)[i] = o;
    }
}

// dst[c][r] = (r<R && c<C) ? src[r][c] : 0 ; dst is Cp x Rp f16
__global__ void transpose_pad(const float* __restrict__ src, f16* __restrict__ dst,
                              int R, int C, int Rp, int Cp)
{
    __shared__ float tile[32][33];
    const int r0 = blockIdx.x * 32, c0 = blockIdx.y * 32;
    const int tx = threadIdx.x, ty = threadIdx.y;  // (32,8)
#pragma unroll
    for (int i = 0; i < 32; i += 8) {
        const int r = r0 + ty + i, c = c0 + tx;
        tile[ty + i][tx] = (r < R && c < C) ? src[r * C + c] : 0.f;
    }
    __syncthreads();
#pragma unroll
    for (int i = 0; i < 32; i += 8) {
        const int c = c0 + ty + i, r = r0 + tx;
        if (c < Cp && r < Rp) dst[c * Rp + r] = (f16)tile[tx][ty + i];
    }
}

// ---------------------------------------------------------------------------
extern "C" void kernel_launch(void* const* d_in, const int* in_sizes, int n_in,
                              void* d_out, int out_size, void* d_ws, size_t ws_size,
                              hipStream_t stream)
{
    const float* x  = (const float*)d_in[0];
    const float* W1 = (const float*)d_in[1];
    const float* b1 = (const float*)d_in[2];
    const float* W2 = (const float*)d_in[3];
    const float* b2 = (const float*)d_in[4];

    char* ws = (char*)d_ws;
    f16* xh   = (f16*)(ws);                                       // 11,796,480 B
    f16* W1t  = (f16*)(ws + 11796480);                            //  2,097,152 B
    f16* W2t  = (f16*)(ws + 11796480 + 2097152);                  //  2,097,152 B
    f16* hbuf = (f16*)(ws + 11796480 + 2 * 2097152);              // 47,185,920 B (h_t, then g16)
    f16* imgG = (f16*)(ws + 11796480 + 2 * 2097152 + 47185920);   //  9,630,720 B

    cvt_x<<<dim3(5760), dim3(256), 0, stream>>>(x, xh, 1474560);
    transpose_pad<<<dim3(16, 64), dim3(32, 8), 0, stream>>>(W1, W1t, 512, 1960, 512, 2048);
    transpose_pad<<<dim3(64, 16), dim3(32, 8), 0, stream>>>(W2, W2t, 1960, 512, 2048, 512);
    // GEMM1 (pipelined): h_t = W1t @ xh^T + b1(row)
    gemm1<<<dim3(1536), dim3(256), 0, stream>>>(W1t, xh, b1, hbuf);
    // fold + normalize + GELU -> f16 image
    fold_gelu<<<dim3(66, 640), dim3(128), 0, stream>>>(hbuf, imgG);
    // unfold via LDS staging -> g16[token][2048] (overwrites hbuf; zero tail)
    unfold_lds<<<dim3(640), dim3(256), 0, stream>>>(imgG, hbuf);
    // out = b2 (broadcast), then GEMM2 split-K=2 accumulates atomically
    bias_fill<<<dim3(5760), dim3(256), 0, stream>>>(b2, (float*)d_out);
    gemm2<<<dim3(768), dim3(256), 0, stream>>>(hbuf, W2t, (float*)d_out);
}

// Round 5
// 234.658 us; speedup vs baseline: 1.0993x; 1.0993x over previous
//
#include <hip/hip_runtime.h>

typedef _Float16 f16;
typedef __attribute__((ext_vector_type(8))) _Float16 half8;
typedef __attribute__((ext_vector_type(4))) _Float16 half4;
typedef __attribute__((ext_vector_type(4))) float f32x4;

#define LDS_AS __attribute__((address_space(3)))
#define GLB_AS __attribute__((address_space(1)))

__device__ __forceinline__ void load16_lds(const f16* g, f16* l) {
    __builtin_amdgcn_global_load_lds((GLB_AS void*)(g), (LDS_AS void*)(l), 16, 0, 0);
}

// stage s+1 in flight while computing stage s; wait only for stage s's 4 loads
#define WAIT4_BARRIER()  asm volatile("s_waitcnt vmcnt(4)\n\ts_barrier" ::: "memory")
#define WAIT0_BARRIER()  asm volatile("s_waitcnt vmcnt(0)\n\ts_barrier" ::: "memory")
#define PLAIN_BARRIER()  asm volatile("s_barrier" ::: "memory")

// ---------------------------------------------------------------------------
// GEMM1: h_t[2048][11520] = W1t[2048][512] @ xh[11520][512]^T + b1(row), f16
// 2-stage pipelined K-loop; XCD swizzle (each xh n-column owned by one XCD).
// ---------------------------------------------------------------------------
__global__ __launch_bounds__(256, 2) void gemm1(
    const f16* __restrict__ A, const f16* __restrict__ Bt,
    const float* __restrict__ bias, f16* __restrict__ C)
{
    const int id  = blockIdx.x;
    const int xcd = id & 7;
    const int r   = id >> 3;
    const int mt  = r & 15;
    const int nt  = xcd + 8 * (r >> 4);
    if (nt >= 90) return;
    const int m0 = mt * 128, n0 = nt * 128;
    const int K = 512, ldc = 11520;

    __shared__ f16 As[2][128 * 32];
    __shared__ f16 Bs[2][128 * 32];
    const int tid  = threadIdx.x;
    const int wave = tid >> 6;
    const int lane = tid & 63;

    const int s0 = tid, s1 = tid + 256;
    const f16* gA0 = A  + (m0 + (s0 >> 2)) * K + (s0 & 3) * 8;
    const f16* gA1 = A  + (m0 + (s1 >> 2)) * K + (s1 & 3) * 8;
    const f16* gB0 = Bt + (n0 + (s0 >> 2)) * K + (s0 & 3) * 8;
    const f16* gB1 = Bt + (n0 + (s1 >> 2)) * K + (s1 & 3) * 8;

    const int wm = (wave >> 1) * 64;
    const int wn = (wave & 1) * 64;
    const int lr = lane & 15;
    const int k8 = (lane >> 4) * 8;

    f32x4 acc[4][4];
#pragma unroll
    for (int i = 0; i < 4; ++i)
#pragma unroll
        for (int j = 0; j < 4; ++j) acc[i][j] = f32x4{0.f, 0.f, 0.f, 0.f};

#define G1_ISSUE(st, k0) do { \
    load16_lds(gA0 + (k0), &As[st][wave * 512]); \
    load16_lds(gA1 + (k0), &As[st][2048 + wave * 512]); \
    load16_lds(gB0 + (k0), &Bs[st][wave * 512]); \
    load16_lds(gB1 + (k0), &Bs[st][2048 + wave * 512]); \
} while (0)

    G1_ISSUE(0, 0);
    const int NS = 16;                 // 512 / 32
    for (int s = 0; s < NS; ++s) {
        const int cur = s & 1;
        if (s + 1 < NS) {
            G1_ISSUE(cur ^ 1, (s + 1) * 32);
            WAIT4_BARRIER();
        } else {
            WAIT0_BARRIER();
        }
        half8 af[4], bf[4];
#pragma unroll
        for (int i = 0; i < 4; ++i)
            af[i] = *(const half8*)&As[cur][(wm + i * 16 + lr) * 32 + k8];
#pragma unroll
        for (int j = 0; j < 4; ++j)
            bf[j] = *(const half8*)&Bs[cur][(wn + j * 16 + lr) * 32 + k8];
#pragma unroll
        for (int i = 0; i < 4; ++i)
#pragma unroll
            for (int j = 0; j < 4; ++j)
                acc[i][j] = __builtin_amdgcn_mfma_f32_16x16x32_f16(
                    af[i], bf[j], acc[i][j], 0, 0, 0);
        PLAIN_BARRIER();
    }

#pragma unroll
    for (int i = 0; i < 4; ++i) {
#pragma unroll
        for (int rr = 0; rr < 4; ++rr) {
            const int row = m0 + wm + i * 16 + (lane >> 4) * 4 + rr;
            const float bvr = (row < 1960) ? bias[row] : 0.f;
#pragma unroll
            for (int j = 0; j < 4; ++j) {
                const int col = n0 + wn + j * 16 + lr;
                C[row * ldc + col] = (f16)(acc[i][j][rr] + bvr);
            }
        }
    }
}

// ---------------------------------------------------------------------------
// GEMM2: out[11520][512] = g16[11520][2048] @ W2t[512][2048]^T + b2(col), f32
// 512 threads: waves 0-3 accumulate k<1024, waves 4-7 k>=1024 (intra-block
// split-K). Each half has its own 2-stage pipelined LDS double-buffer
// (64 KB total). Halves combine through LDS; one plain store, no atomics.
// ---------------------------------------------------------------------------
__global__ __launch_bounds__(512, 2) void gemm2(
    const f16* __restrict__ A, const f16* __restrict__ Bt,
    const float* __restrict__ bias, float* __restrict__ Cout)
{
    const int id  = blockIdx.x;
    const int xcd = id & 7;
    const int j2  = id >> 3;
    const int nt  = j2 & 3;
    const int mt  = (j2 >> 2) * 8 + xcd;
    if (mt >= 90) return;
    const int m0 = mt * 128, n0 = nt * 128;

    __shared__ f16 smem[32768];        // [half][stage][A 4096 | B 4096] f16
    const int tid  = threadIdx.x;
    const int half = tid >> 8;
    const int t    = tid & 255;
    const int wave = (tid >> 6) & 3;   // wave index within half
    const int lane = tid & 63;

    const int kbase = half * 1024;
    const int s1 = t + 256;
    const f16* gA0 = A  + (m0 + (t  >> 2)) * 2048 + kbase + (t  & 3) * 8;
    const f16* gA1 = A  + (m0 + (s1 >> 2)) * 2048 + kbase + (s1 & 3) * 8;
    const f16* gB0 = Bt + (n0 + (t  >> 2)) * 2048 + kbase + (t  & 3) * 8;
    const f16* gB1 = Bt + (n0 + (s1 >> 2)) * 2048 + kbase + (s1 & 3) * 8;
    f16* hb = &smem[half * 16384];

    const int wm = (wave >> 1) * 64;
    const int wn = (wave & 1) * 64;
    const int lr = lane & 15;
    const int k8 = (lane >> 4) * 8;

    f32x4 acc[4][4];
#pragma unroll
    for (int i = 0; i < 4; ++i)
#pragma unroll
        for (int j = 0; j < 4; ++j) acc[i][j] = f32x4{0.f, 0.f, 0.f, 0.f};

#define G2_ISSUE(st, k0) do { \
    f16* sb = hb + (st) * 8192; \
    load16_lds(gA0 + (k0), sb + wave * 512); \
    load16_lds(gA1 + (k0), sb + 2048 + wave * 512); \
    load16_lds(gB0 + (k0), sb + 4096 + wave * 512); \
    load16_lds(gB1 + (k0), sb + 6144 + wave * 512); \
} while (0)

    G2_ISSUE(0, 0);
    const int NS = 32;                 // 1024 / 32 per half
    for (int s = 0; s < NS; ++s) {
        const int cur = s & 1;
        if (s + 1 < NS) {
            G2_ISSUE(cur ^ 1, (s + 1) * 32);
            WAIT4_BARRIER();
        } else {
            WAIT0_BARRIER();
        }
        const f16* sa = hb + cur * 8192;
        const f16* sbB = sa + 4096;
        half8 af[4], bf[4];
#pragma unroll
        for (int i = 0; i < 4; ++i)
            af[i] = *(const half8*)&sa[(wm + i * 16 + lr) * 32 + k8];
#pragma unroll
        for (int j = 0; j < 4; ++j)
            bf[j] = *(const half8*)&sbB[(wn + j * 16 + lr) * 32 + k8];
#pragma unroll
        for (int i = 0; i < 4; ++i)
#pragma unroll
            for (int j = 0; j < 4; ++j)
                acc[i][j] = __builtin_amdgcn_mfma_f32_16x16x32_f16(
                    af[i], bf[j], acc[i][j], 0, 0, 0);
        PLAIN_BARRIER();
    }

    // combine halves through LDS (64 KB = one 128x128 f32 tile)
    float* accl = (float*)smem;
    if (half == 1) {
#pragma unroll
        for (int i = 0; i < 4; ++i)
#pragma unroll
            for (int rr = 0; rr < 4; ++rr) {
                const int row = wm + i * 16 + (lane >> 4) * 4 + rr;
#pragma unroll
                for (int j = 0; j < 4; ++j)
                    accl[row * 128 + wn + j * 16 + lr] = acc[i][j][rr];
            }
    }
    __syncthreads();
    if (half == 0) {
#pragma unroll
        for (int j = 0; j < 4; ++j) {
            const int col = wn + j * 16 + lr;
            const float bv = bias[n0 + col];
#pragma unroll
            for (int i = 0; i < 4; ++i) {
#pragma unroll
                for (int rr = 0; rr < 4; ++rr) {
                    const int row = wm + i * 16 + (lane >> 4) * 4 + rr;
                    Cout[(m0 + row) * 512 + n0 + col] =
                        acc[i][j][rr] + accl[row * 128 + col] + bv;
                }
            }
        }
    }
}

// ---------------------------------------------------------------------------
// fold (gather form) + normalize + exact GELU, h_t[2048][11520] -> imgG f16
// ---------------------------------------------------------------------------
__global__ void fold_gelu(const f16* __restrict__ h_t, f16* __restrict__ imgG)
{
    const int r  = blockIdx.x;        // 0..65
    const int bc = blockIdx.y;        // bp*40 + cch
    const int bp  = bc / 40;
    const int cch = bc % 40;
    const int c = threadIdx.x;
    if (c >= 114) return;
    float outv = 0.f;
    if (r >= 3 && r < 63 && c >= 3 && c < 111) {
        const int qr = r / 3, rm = r % 3;
        const int qc = c / 3, cm = c % 3;
        int kis[3], ohs[3], nr = 0;
        int kjs[3], ows[3], nc = 0;
#pragma unroll
        for (int t = 0; t < 3; ++t) {
            const int ki = rm + 3 * t, oh = qr - t;
            if (ki < 7 && oh >= 0 && oh < 20) { kis[nr] = ki; ohs[nr] = oh; ++nr; }
            const int kj = cm + 3 * t, ow = qc - t;
            if (kj < 7 && ow >= 0 && ow < 36) { kjs[nc] = kj; ows[nc] = ow; ++nc; }
        }
        float sum = 0.f;
        for (int a = 0; a < nr; ++a)
            for (int b = 0; b < nc; ++b) {
                const int n = cch * 49 + kis[a] * 7 + kjs[b];
                const int token = bp * 720 + ohs[a] * 36 + ows[b];
                sum += (float)h_t[n * 11520 + token];
            }
        const float xv = sum / (float)(nr * nc);
        outv = 0.5f * xv * (1.f + erff(xv * 0.70710678118654752f));
    }
    imgG[(bc * 66 + r) * 114 + c] = (f16)outv;
}

// ---------------------------------------------------------------------------
// unfold: stage one channel image (15 KB) in LDS, then gather + write g16.
// Block per (bp,cch); cch>=36 blocks also zero tail cols [1960,2048).
// ---------------------------------------------------------------------------
__global__ __launch_bounds__(256) void unfold_lds(
    const f16* __restrict__ imgG, f16* __restrict__ g16)
{
    __shared__ f16 ch[7524];
    const int bc = blockIdx.x;        // 0..639
    const int bp = bc / 40, cch = bc % 40;
    const float* src = (const float*)(imgG + bc * 7524);
    float* dst = (float*)ch;
    for (int i = threadIdx.x; i < 3762; i += 256) dst[i] = src[i];
    __syncthreads();
    const int tokbase = bp * 720;
    const int colbase = cch * 49;
    for (int flat = threadIdx.x; flat < 35280; flat += 256) {
        const int l = flat / 49, k = flat - l * 49;
        const int oh = l / 36, ow = l - oh * 36;
        const int ki = k / 7,  kj = k - ki * 7;
        g16[(tokbase + l) * 2048 + colbase + k] =
            ch[(oh * 3 + ki) * 114 + ow * 3 + kj];
    }
    if (cch >= 36) {
        const int cb = 1960 + (cch - 36) * 22;   // 4 blocks x 22 cols = 88
        for (int flat = threadIdx.x; flat < 720 * 22; flat += 256) {
            const int l = flat / 22, k = flat - l * 22;
            g16[(tokbase + l) * 2048 + cb + k] = (f16)0.f;
        }
    }
}

// ---------------------------------------------------------------------------
__global__ void cvt_x(const float* __restrict__ x, f16* __restrict__ xh, int n4)
{
    const int i = blockIdx.x * 256 + threadIdx.x;
    if (i < n4) {
        const float4 v = ((const float4*)x)[i];
        half4 o;
        o[0] = (f16)v.x; o[1] = (f16)v.y; o[2] = (f16)v.z; o[3] = (f16)v.w;
        ((half4*)xh)[i] = o;
    }
}

// dst[c][r] = (r<R && c<C) ? src[r][c] : 0 ; dst is Cp x Rp f16
__global__ void transpose_pad(const float* __restrict__ src, f16* __restrict__ dst,
                              int R, int C, int Rp, int Cp)
{
    __shared__ float tile[32][33];
    const int r0 = blockIdx.x * 32, c0 = blockIdx.y * 32;
    const int tx = threadIdx.x, ty = threadIdx.y;  // (32,8)
#pragma unroll
    for (int i = 0; i < 32; i += 8) {
        const int r = r0 + ty + i, c = c0 + tx;
        tile[ty + i][tx] = (r < R && c < C) ? src[r * C + c] : 0.f;
    }
    __syncthreads();
#pragma unroll
    for (int i = 0; i < 32; i += 8) {
        const int c = c0 + ty + i, r = r0 + tx;
        if (c < Cp && r < Rp) dst[c * Rp + r] = (f16)tile[tx][ty + i];
    }
}

// ---------------------------------------------------------------------------
extern "C" void kernel_launch(void* const* d_in, const int* in_sizes, int n_in,
                              void* d_out, int out_size, void* d_ws, size_t ws_size,
                              hipStream_t stream)
{
    const float* x  = (const float*)d_in[0];
    const float* W1 = (const float*)d_in[1];
    const float* b1 = (const float*)d_in[2];
    const float* W2 = (const float*)d_in[3];
    const float* b2 = (const float*)d_in[4];

    char* ws = (char*)d_ws;
    f16* xh   = (f16*)(ws);                                       // 11,796,480 B
    f16* W1t  = (f16*)(ws + 11796480);                            //  2,097,152 B
    f16* W2t  = (f16*)(ws + 11796480 + 2097152);                  //  2,097,152 B
    f16* hbuf = (f16*)(ws + 11796480 + 2 * 2097152);              // 47,185,920 B (h_t, then g16)
    f16* imgG = (f16*)(ws + 11796480 + 2 * 2097152 + 47185920);   //  9,630,720 B

    cvt_x<<<dim3(5760), dim3(256), 0, stream>>>(x, xh, 1474560);
    transpose_pad<<<dim3(16, 64), dim3(32, 8), 0, stream>>>(W1, W1t, 512, 1960, 512, 2048);
    transpose_pad<<<dim3(64, 16), dim3(32, 8), 0, stream>>>(W2, W2t, 1960, 512, 2048, 512);
    // GEMM1 (pipelined): h_t = W1t @ xh^T + b1(row)
    gemm1<<<dim3(1536), dim3(256), 0, stream>>>(W1t, xh, b1, hbuf);
    // fold + normalize + GELU -> f16 image
    fold_gelu<<<dim3(66, 640), dim3(128), 0, stream>>>(hbuf, imgG);
    // unfold via LDS staging -> g16[token][2048] (overwrites hbuf; zero tail)
    unfold_lds<<<dim3(640), dim3(256), 0, stream>>>(imgG, hbuf);
    // GEMM2 (intra-block split-K, no atomics): out = g16 @ W2t^T + b2
    gemm2<<<dim3(384), dim3(512), 0, stream>>>(hbuf, W2t, b2, (float*)d_out);
}

// Round 6
// 232.963 us; speedup vs baseline: 1.1073x; 1.0073x over previous
//
#include <hip/hip_runtime.h>

typedef _Float16 f16;
typedef __attribute__((ext_vector_type(8))) _Float16 half8;
typedef __attribute__((ext_vector_type(4))) _Float16 half4;
typedef __attribute__((ext_vector_type(4))) float f32x4;

#define LDS_AS __attribute__((address_space(3)))
#define GLB_AS __attribute__((address_space(1)))

__device__ __forceinline__ void load16_lds(const f16* g, f16* l) {
    __builtin_amdgcn_global_load_lds((GLB_AS void*)(g), (LDS_AS void*)(l), 16, 0, 0);
}

#define WAIT4_BARRIER()  asm volatile("s_waitcnt vmcnt(4)\n\ts_barrier" ::: "memory")
#define WAIT3_BARRIER()  asm volatile("s_waitcnt vmcnt(3)\n\ts_barrier" ::: "memory")
#define WAIT0_BARRIER()  asm volatile("s_waitcnt vmcnt(0)\n\ts_barrier" ::: "memory")
#define PLAIN_BARRIER()  asm volatile("s_barrier" ::: "memory")

// ---------------------------------------------------------------------------
// GEMM1: h_t[2048][11520] = W1t[2048][512] @ xh[11520][512]^T + b1(row), f16
// 2-stage pipelined K-loop; XCD swizzle (each xh n-column owned by one XCD).
// ---------------------------------------------------------------------------
__global__ __launch_bounds__(256, 3) void gemm1(
    const f16* __restrict__ A, const f16* __restrict__ Bt,
    const float* __restrict__ bias, f16* __restrict__ C)
{
    const int id  = blockIdx.x;
    const int xcd = id & 7;
    const int r   = id >> 3;
    const int mt  = r & 15;
    const int nt  = xcd + 8 * (r >> 4);
    if (nt >= 90) return;
    const int m0 = mt * 128, n0 = nt * 128;
    const int K = 512, ldc = 11520;

    __shared__ f16 As[2][128 * 32];
    __shared__ f16 Bs[2][128 * 32];
    const int tid  = threadIdx.x;
    const int wave = tid >> 6;
    const int lane = tid & 63;

    const int s0 = tid, s1 = tid + 256;
    const f16* gA0 = A  + (m0 + (s0 >> 2)) * K + (s0 & 3) * 8;
    const f16* gA1 = A  + (m0 + (s1 >> 2)) * K + (s1 & 3) * 8;
    const f16* gB0 = Bt + (n0 + (s0 >> 2)) * K + (s0 & 3) * 8;
    const f16* gB1 = Bt + (n0 + (s1 >> 2)) * K + (s1 & 3) * 8;

    const int wm = (wave >> 1) * 64;
    const int wn = (wave & 1) * 64;
    const int lr = lane & 15;
    const int k8 = (lane >> 4) * 8;

    f32x4 acc[4][4];
#pragma unroll
    for (int i = 0; i < 4; ++i)
#pragma unroll
        for (int j = 0; j < 4; ++j) acc[i][j] = f32x4{0.f, 0.f, 0.f, 0.f};

#define G1_ISSUE(st, k0) do { \
    load16_lds(gA0 + (k0), &As[st][wave * 512]); \
    load16_lds(gA1 + (k0), &As[st][2048 + wave * 512]); \
    load16_lds(gB0 + (k0), &Bs[st][wave * 512]); \
    load16_lds(gB1 + (k0), &Bs[st][2048 + wave * 512]); \
} while (0)

    G1_ISSUE(0, 0);
    const int NS = 16;                 // 512 / 32
    for (int s = 0; s < NS; ++s) {
        const int cur = s & 1;
        if (s + 1 < NS) {
            G1_ISSUE(cur ^ 1, (s + 1) * 32);
            WAIT4_BARRIER();
        } else {
            WAIT0_BARRIER();
        }
        half8 af[4], bf[4];
#pragma unroll
        for (int i = 0; i < 4; ++i)
            af[i] = *(const half8*)&As[cur][(wm + i * 16 + lr) * 32 + k8];
#pragma unroll
        for (int j = 0; j < 4; ++j)
            bf[j] = *(const half8*)&Bs[cur][(wn + j * 16 + lr) * 32 + k8];
#pragma unroll
        for (int i = 0; i < 4; ++i)
#pragma unroll
            for (int j = 0; j < 4; ++j)
                acc[i][j] = __builtin_amdgcn_mfma_f32_16x16x32_f16(
                    af[i], bf[j], acc[i][j], 0, 0, 0);
        PLAIN_BARRIER();
    }

#pragma unroll
    for (int i = 0; i < 4; ++i) {
#pragma unroll
        for (int rr = 0; rr < 4; ++rr) {
            const int row = m0 + wm + i * 16 + (lane >> 4) * 4 + rr;
            const float bvr = (row < 1960) ? bias[row] : 0.f;
#pragma unroll
            for (int j = 0; j < 4; ++j) {
                const int col = n0 + wn + j * 16 + lr;
                C[row * ldc + col] = (f16)(acc[i][j][rr] + bvr);
            }
        }
    }
}

// ---------------------------------------------------------------------------
// GEMM2: out[11520][512] = g16[11520][2048] @ W2t[512][2048]^T + b2(col), f32
// 128x64 tile, 720 active blocks (2.8/CU). 512 threads: waves 0-3 k<1024,
// waves 4-7 k>=1024 (intra-block split-K), each half 2-stage pipelined.
// Swizzle id = nt*96 + mt (96%8==0) -> all 8 n-blocks of mt on XCD mt%8.
// ---------------------------------------------------------------------------
__global__ __launch_bounds__(512, 4) void gemm2(
    const f16* __restrict__ A, const f16* __restrict__ Bt,
    const float* __restrict__ bias, float* __restrict__ Cout)
{
    const int id = blockIdx.x;
    const int nt = id / 96;            // 0..7
    const int mt = id % 96;
    if (mt >= 90) return;
    const int m0 = mt * 128, n0 = nt * 64;

    __shared__ f16 smem[24576];        // [half][stage][A 4096 | B 2048] f16
    const int tid  = threadIdx.x;
    const int half = tid >> 8;
    const int t    = tid & 255;
    const int wave = (tid >> 6) & 3;
    const int lane = tid & 63;

    const int kbase = half * 1024;
    const int s1 = t + 256;
    const f16* gA0 = A  + (m0 + (t  >> 2)) * 2048 + kbase + (t  & 3) * 8;
    const f16* gA1 = A  + (m0 + (s1 >> 2)) * 2048 + kbase + (s1 & 3) * 8;
    const f16* gB0 = Bt + (n0 + (t  >> 2)) * 2048 + kbase + (t  & 3) * 8;
    f16* hb = &smem[half * 12288];

    const int wm = (wave >> 1) * 64;   // wave tile 64M x 32N
    const int wn = (wave & 1) * 32;
    const int lr = lane & 15;
    const int k8 = (lane >> 4) * 8;

    f32x4 acc[4][2];
#pragma unroll
    for (int i = 0; i < 4; ++i)
#pragma unroll
        for (int j = 0; j < 2; ++j) acc[i][j] = f32x4{0.f, 0.f, 0.f, 0.f};

#define G2_ISSUE(st, k0) do { \
    f16* sb = hb + (st) * 6144; \
    load16_lds(gA0 + (k0), sb + wave * 512); \
    load16_lds(gA1 + (k0), sb + 2048 + wave * 512); \
    load16_lds(gB0 + (k0), sb + 4096 + wave * 512); \
} while (0)

    G2_ISSUE(0, 0);
    const int NS = 32;                 // 1024 / 32 per half
    for (int s = 0; s < NS; ++s) {
        const int cur = s & 1;
        if (s + 1 < NS) {
            G2_ISSUE(cur ^ 1, (s + 1) * 32);
            WAIT3_BARRIER();
        } else {
            WAIT0_BARRIER();
        }
        const f16* sa = hb + cur * 6144;
        half8 af[4], bf[2];
#pragma unroll
        for (int i = 0; i < 4; ++i)
            af[i] = *(const half8*)&sa[(wm + i * 16 + lr) * 32 + k8];
#pragma unroll
        for (int j = 0; j < 2; ++j)
            bf[j] = *(const half8*)&sa[4096 + (wn + j * 16 + lr) * 32 + k8];
#pragma unroll
        for (int i = 0; i < 4; ++i)
#pragma unroll
            for (int j = 0; j < 2; ++j)
                acc[i][j] = __builtin_amdgcn_mfma_f32_16x16x32_f16(
                    af[i], bf[j], acc[i][j], 0, 0, 0);
        PLAIN_BARRIER();
    }

    // combine halves through LDS (128x64 f32 = 32 KB, fits the 48 KB block)
    float* accl = (float*)smem;
    if (half == 1) {
#pragma unroll
        for (int i = 0; i < 4; ++i)
#pragma unroll
            for (int rr = 0; rr < 4; ++rr) {
                const int row = wm + i * 16 + (lane >> 4) * 4 + rr;
#pragma unroll
                for (int j = 0; j < 2; ++j)
                    accl[row * 64 + wn + j * 16 + lr] = acc[i][j][rr];
            }
    }
    __syncthreads();
    if (half == 0) {
#pragma unroll
        for (int j = 0; j < 2; ++j) {
            const int col = wn + j * 16 + lr;
            const float bv = bias[n0 + col];
#pragma unroll
            for (int i = 0; i < 4; ++i) {
#pragma unroll
                for (int rr = 0; rr < 4; ++rr) {
                    const int row = wm + i * 16 + (lane >> 4) * 4 + rr;
                    Cout[(m0 + row) * 512 + n0 + col] =
                        acc[i][j][rr] + accl[row * 64 + col] + bv;
                }
            }
        }
    }
}

// ---------------------------------------------------------------------------
// fold (gather form) + normalize + exact GELU, h_t[2048][11520] -> imgG f16
// ---------------------------------------------------------------------------
__global__ void fold_gelu(const f16* __restrict__ h_t, f16* __restrict__ imgG)
{
    const int r  = blockIdx.x;        // 0..65
    const int bc = blockIdx.y;        // bp*40 + cch
    const int bp  = bc / 40;
    const int cch = bc % 40;
    const int c = threadIdx.x;
    if (c >= 114) return;
    float outv = 0.f;
    if (r >= 3 && r < 63 && c >= 3 && c < 111) {
        const int qr = r / 3, rm = r % 3;
        const int qc = c / 3, cm = c % 3;
        int kis[3], ohs[3], nr = 0;
        int kjs[3], ows[3], nc = 0;
#pragma unroll
        for (int t = 0; t < 3; ++t) {
            const int ki = rm + 3 * t, oh = qr - t;
            if (ki < 7 && oh >= 0 && oh < 20) { kis[nr] = ki; ohs[nr] = oh; ++nr; }
            const int kj = cm + 3 * t, ow = qc - t;
            if (kj < 7 && ow >= 0 && ow < 36) { kjs[nc] = kj; ows[nc] = ow; ++nc; }
        }
        float sum = 0.f;
        for (int a = 0; a < nr; ++a)
            for (int b = 0; b < nc; ++b) {
                const int n = cch * 49 + kis[a] * 7 + kjs[b];
                const int token = bp * 720 + ohs[a] * 36 + ows[b];
                sum += (float)h_t[n * 11520 + token];
            }
        const float xv = sum / (float)(nr * nc);
        outv = 0.5f * xv * (1.f + erff(xv * 0.70710678118654752f));
    }
    imgG[(bc * 66 + r) * 114 + c] = (f16)outv;
}

// ---------------------------------------------------------------------------
// unfold: stage one channel image (15 KB) in LDS, then gather + write g16.
// Block per (bp,cch); cch>=36 blocks also zero tail cols [1960,2048).
// ---------------------------------------------------------------------------
__global__ __launch_bounds__(256) void unfold_lds(
    const f16* __restrict__ imgG, f16* __restrict__ g16)
{
    __shared__ f16 ch[7524];
    const int bc = blockIdx.x;        // 0..639
    const int bp = bc / 40, cch = bc % 40;
    const float* src = (const float*)(imgG + bc * 7524);
    float* dst = (float*)ch;
    for (int i = threadIdx.x; i < 3762; i += 256) dst[i] = src[i];
    __syncthreads();
    const int tokbase = bp * 720;
    const int colbase = cch * 49;
    for (int flat = threadIdx.x; flat < 35280; flat += 256) {
        const int l = flat / 49, k = flat - l * 49;
        const int oh = l / 36, ow = l - oh * 36;
        const int ki = k / 7,  kj = k - ki * 7;
        g16[(tokbase + l) * 2048 + colbase + k] =
            ch[(oh * 3 + ki) * 114 + ow * 3 + kj];
    }
    if (cch >= 36) {
        const int cb = 1960 + (cch - 36) * 22;   // 4 blocks x 22 cols = 88
        for (int flat = threadIdx.x; flat < 720 * 22; flat += 256) {
            const int l = flat / 22, k = flat - l * 22;
            g16[(tokbase + l) * 2048 + cb + k] = (f16)0.f;
        }
    }
}

// ---------------------------------------------------------------------------
// prep: fuses x->f16 convert + both weight transposes (one dispatch).
// blocks [0,5760): cvt; [5760,6784): W1 -> W1t; [6784,7808): W2 -> W2t
// ---------------------------------------------------------------------------
__global__ __launch_bounds__(256) void prep(
    const float* __restrict__ x, f16* __restrict__ xh,
    const float* __restrict__ W1, f16* __restrict__ W1t,
    const float* __restrict__ W2, f16* __restrict__ W2t)
{
    __shared__ float tile[32][33];
    const int b = blockIdx.x, t = threadIdx.x;
    if (b < 5760) {
        const int i = b * 256 + t;     // < 1474560 float4s
        const float4 v = ((const float4*)x)[i];
        half4 o;
        o[0] = (f16)v.x; o[1] = (f16)v.y; o[2] = (f16)v.z; o[3] = (f16)v.w;
        ((half4*)xh)[i] = o;
        return;
    }
    const float* src; f16* dst; int R, C, Rp, Cp, bx, by;
    if (b < 6784) {
        const int local = b - 5760;    // grid (16,64)
        bx = local & 15; by = local >> 4;
        src = W1; dst = W1t; R = 512; C = 1960; Rp = 512; Cp = 2048;
    } else {
        const int local = b - 6784;    // grid (64,16)
        bx = local & 63; by = local >> 6;
        src = W2; dst = W2t; R = 1960; C = 512; Rp = 2048; Cp = 512;
    }
    const int r0 = bx * 32, c0 = by * 32;
    const int tx = t & 31, ty = t >> 5;
#pragma unroll
    for (int i = 0; i < 32; i += 8) {
        const int r = r0 + ty + i, c = c0 + tx;
        tile[ty + i][tx] = (r < R && c < C) ? src[r * C + c] : 0.f;
    }
    __syncthreads();
#pragma unroll
    for (int i = 0; i < 32; i += 8) {
        const int c = c0 + ty + i, r = r0 + tx;
        if (c < Cp && r < Rp) dst[c * Rp + r] = (f16)tile[tx][ty + i];
    }
}

// ---------------------------------------------------------------------------
extern "C" void kernel_launch(void* const* d_in, const int* in_sizes, int n_in,
                              void* d_out, int out_size, void* d_ws, size_t ws_size,
                              hipStream_t stream)
{
    const float* x  = (const float*)d_in[0];
    const float* W1 = (const float*)d_in[1];
    const float* b1 = (const float*)d_in[2];
    const float* W2 = (const float*)d_in[3];
    const float* b2 = (const float*)d_in[4];

    char* ws = (char*)d_ws;
    f16* xh   = (f16*)(ws);                                       // 11,796,480 B
    f16* W1t  = (f16*)(ws + 11796480);                            //  2,097,152 B
    f16* W2t  = (f16*)(ws + 11796480 + 2097152);                  //  2,097,152 B
    f16* hbuf = (f16*)(ws + 11796480 + 2 * 2097152);              // 47,185,920 B (h_t, then g16)
    f16* imgG = (f16*)(ws + 11796480 + 2 * 2097152 + 47185920);   //  9,630,720 B

    // fused convert + transposes
    prep<<<dim3(7808), dim3(256), 0, stream>>>(x, xh, W1, W1t, W2, W2t);
    // GEMM1 (pipelined): h_t = W1t @ xh^T + b1(row)
    gemm1<<<dim3(1536), dim3(256), 0, stream>>>(W1t, xh, b1, hbuf);
    // fold + normalize + GELU -> f16 image
    fold_gelu<<<dim3(66, 640), dim3(128), 0, stream>>>(hbuf, imgG);
    // unfold via LDS staging -> g16[token][2048] (overwrites hbuf; zero tail)
    unfold_lds<<<dim3(640), dim3(256), 0, stream>>>(imgG, hbuf);
    // GEMM2 (128x64, intra-block split-K, XCD-pinned): out = g16 @ W2t^T + b2
    gemm2<<<dim3(768), dim3(512), 0, stream>>>(hbuf, W2t, b2, (float*)d_out);
}

// Round 8
// 226.860 us; speedup vs baseline: 1.1371x; 1.0269x over previous
//
#include <hip/hip_runtime.h>

typedef _Float16 f16;
typedef __attribute__((ext_vector_type(8))) _Float16 half8;
typedef __attribute__((ext_vector_type(4))) _Float16 half4;
typedef __attribute__((ext_vector_type(4))) float f32x4;

#define LDS_AS __attribute__((address_space(3)))
#define GLB_AS __attribute__((address_space(1)))

__device__ __forceinline__ void load16_lds(const f16* g, f16* l) {
    __builtin_amdgcn_global_load_lds((GLB_AS void*)(g), (LDS_AS void*)(l), 16, 0, 0);
}

#define WAIT8_BARRIER()  asm volatile("s_waitcnt vmcnt(8)\n\ts_barrier" ::: "memory")
#define WAIT4_BARRIER()  asm volatile("s_waitcnt vmcnt(4)\n\ts_barrier" ::: "memory")
#define WAIT0_BARRIER()  asm volatile("s_waitcnt vmcnt(0)\n\ts_barrier" ::: "memory")
// end-of-iteration barrier: lgkmcnt(0) guarantees this wave's ds_reads have
// retired before any wave can issue the next DMA into the consumed buffer
// (closes the MFMA-sink race — MFMAs are not memory ops, so "memory" clobber
// alone does not pin their lgkm waits before s_barrier).
#define ENDBAR()         asm volatile("s_waitcnt lgkmcnt(0)\n\ts_barrier" ::: "memory")

// ---------------------------------------------------------------------------
// GEMM1: h_t[2048][11520] = W1t[2048][512] @ xh[11520][512]^T + b1(row), f16
// 2-stage pipelined K-loop; XCD swizzle (each xh n-column owned by one XCD).
// (R6-passing version; only the end barrier hardened.)
// ---------------------------------------------------------------------------
__global__ __launch_bounds__(256, 3) void gemm1(
    const f16* __restrict__ A, const f16* __restrict__ Bt,
    const float* __restrict__ bias, f16* __restrict__ C)
{
    const int id  = blockIdx.x;
    const int xcd = id & 7;
    const int r   = id >> 3;
    const int mt  = r & 15;
    const int nt  = xcd + 8 * (r >> 4);
    if (nt >= 90) return;
    const int m0 = mt * 128, n0 = nt * 128;
    const int K = 512, ldc = 11520;

    __shared__ f16 As[2][128 * 32];
    __shared__ f16 Bs[2][128 * 32];
    const int tid  = threadIdx.x;
    const int wave = tid >> 6;
    const int lane = tid & 63;

    const int s0 = tid, s1 = tid + 256;
    const f16* gA0 = A  + (m0 + (s0 >> 2)) * K + (s0 & 3) * 8;
    const f16* gA1 = A  + (m0 + (s1 >> 2)) * K + (s1 & 3) * 8;
    const f16* gB0 = Bt + (n0 + (s0 >> 2)) * K + (s0 & 3) * 8;
    const f16* gB1 = Bt + (n0 + (s1 >> 2)) * K + (s1 & 3) * 8;

    const int wm = (wave >> 1) * 64;
    const int wn = (wave & 1) * 64;
    const int lr = lane & 15;
    const int k8 = (lane >> 4) * 8;

    f32x4 acc[4][4];
#pragma unroll
    for (int i = 0; i < 4; ++i)
#pragma unroll
        for (int j = 0; j < 4; ++j) acc[i][j] = f32x4{0.f, 0.f, 0.f, 0.f};

#define G1_ISSUE(st, k0) do { \
    load16_lds(gA0 + (k0), &As[st][wave * 512]); \
    load16_lds(gA1 + (k0), &As[st][2048 + wave * 512]); \
    load16_lds(gB0 + (k0), &Bs[st][wave * 512]); \
    load16_lds(gB1 + (k0), &Bs[st][2048 + wave * 512]); \
} while (0)

    G1_ISSUE(0, 0);
    const int NS = 16;                 // 512 / 32
    for (int s = 0; s < NS; ++s) {
        const int cur = s & 1;
        if (s + 1 < NS) {
            G1_ISSUE(cur ^ 1, (s + 1) * 32);
            WAIT4_BARRIER();
        } else {
            WAIT0_BARRIER();
        }
        half8 af[4], bf[4];
#pragma unroll
        for (int i = 0; i < 4; ++i)
            af[i] = *(const half8*)&As[cur][(wm + i * 16 + lr) * 32 + k8];
#pragma unroll
        for (int j = 0; j < 4; ++j)
            bf[j] = *(const half8*)&Bs[cur][(wn + j * 16 + lr) * 32 + k8];
#pragma unroll
        for (int i = 0; i < 4; ++i)
#pragma unroll
            for (int j = 0; j < 4; ++j)
                acc[i][j] = __builtin_amdgcn_mfma_f32_16x16x32_f16(
                    af[i], bf[j], acc[i][j], 0, 0, 0);
        ENDBAR();
    }

#pragma unroll
    for (int i = 0; i < 4; ++i) {
#pragma unroll
        for (int rr = 0; rr < 4; ++rr) {
            const int row = m0 + wm + i * 16 + (lane >> 4) * 4 + rr;
            const float bvr = (row < 1960) ? bias[row] : 0.f;
#pragma unroll
            for (int j = 0; j < 4; ++j) {
                const int col = n0 + wn + j * 16 + lr;
                C[row * ldc + col] = (f16)(acc[i][j][rr] + bvr);
            }
        }
    }
}

// ---------------------------------------------------------------------------
// GEMM2: out[11520][512] = g16[11520][2048] @ W2t[512][2048]^T + b2(col), f32
// 128x128 tile, 256 threads, 3-stage pipelined LDS (48 KB). Prefetch
// distance 2; vmcnt(8/4/0) — in-flight prefetch never drained mid-loop.
// XCD swizzle: the 4 n-blocks sharing an A row-tile land on one XCD.
// ---------------------------------------------------------------------------
__global__ __launch_bounds__(256, 2) void gemm2(
    const f16* __restrict__ A, const f16* __restrict__ Bt,
    const float* __restrict__ bias, float* __restrict__ Cout)
{
    const int id  = blockIdx.x;
    const int xcd = id & 7;
    const int j2  = id >> 3;
    const int nt  = j2 & 3;
    const int mt  = (j2 >> 2) * 8 + xcd;
    if (mt >= 90) return;
    const int m0 = mt * 128, n0 = nt * 128;

    __shared__ f16 smem[24576];        // 48 KB: 3 stages x (A 4096 | B 4096)
    const int tid  = threadIdx.x;
    const int wave = tid >> 6;
    const int lane = tid & 63;

    const int s1 = tid + 256;
    const f16* gA0 = A  + (m0 + (tid >> 2)) * 2048 + (tid & 3) * 8;
    const f16* gA1 = A  + (m0 + (s1 >> 2)) * 2048 + (s1 & 3) * 8;
    const f16* gB0 = Bt + (n0 + (tid >> 2)) * 2048 + (tid & 3) * 8;
    const f16* gB1 = Bt + (n0 + (s1 >> 2)) * 2048 + (s1 & 3) * 8;

    const int wm = (wave >> 1) * 64;
    const int wn = (wave & 1) * 64;
    const int lr = lane & 15;
    const int k8 = (lane >> 4) * 8;

    f32x4 acc[4][4];
#pragma unroll
    for (int i = 0; i < 4; ++i)
#pragma unroll
        for (int j = 0; j < 4; ++j) acc[i][j] = f32x4{0.f, 0.f, 0.f, 0.f};

#define G2_ISSUE(st, k0) do { \
    f16* sb_ = &smem[(st) * 8192]; \
    load16_lds(gA0 + (k0), sb_ + wave * 512); \
    load16_lds(gA1 + (k0), sb_ + 2048 + wave * 512); \
    load16_lds(gB0 + (k0), sb_ + 4096 + wave * 512); \
    load16_lds(gB1 + (k0), sb_ + 6144 + wave * 512); \
} while (0)

    G2_ISSUE(0, 0);
    G2_ISSUE(1, 32);
    const int NS = 64;                 // 2048 / 32
    int cur = 0;                       // buffer to consume (= s % 3)
    for (int s = 0; s < NS; ++s) {
        if (s + 2 < NS) {
            int pre = cur + 2; if (pre >= 3) pre -= 3;
            G2_ISSUE(pre, (s + 2) * 32);
        }
        const int rem = NS - 1 - s;
        if (rem >= 2)      WAIT8_BARRIER();
        else if (rem == 1) WAIT4_BARRIER();
        else               WAIT0_BARRIER();
        const f16* sa = &smem[cur * 8192];
        half8 af[4], bf[4];
#pragma unroll
        for (int i = 0; i < 4; ++i)
            af[i] = *(const half8*)&sa[(wm + i * 16 + lr) * 32 + k8];
#pragma unroll
        for (int j = 0; j < 4; ++j)
            bf[j] = *(const half8*)&sa[4096 + (wn + j * 16 + lr) * 32 + k8];
#pragma unroll
        for (int i = 0; i < 4; ++i)
#pragma unroll
            for (int j = 0; j < 4; ++j)
                acc[i][j] = __builtin_amdgcn_mfma_f32_16x16x32_f16(
                    af[i], bf[j], acc[i][j], 0, 0, 0);
        ENDBAR();
        ++cur; if (cur >= 3) cur = 0;
    }

#pragma unroll
    for (int j = 0; j < 4; ++j) {
        const int col = n0 + wn + j * 16 + lr;
        const float bv = bias[col];
#pragma unroll
        for (int i = 0; i < 4; ++i) {
            const int rbase = m0 + wm + i * 16 + (lane >> 4) * 4;
#pragma unroll
            for (int rr = 0; rr < 4; ++rr)
                Cout[(rbase + rr) * 512 + col] = acc[i][j][rr] + bv;
        }
    }
}

// ---------------------------------------------------------------------------
// fold (gather form) + normalize + exact GELU, h_t[2048][11520] -> imgG f16
// ---------------------------------------------------------------------------
__global__ void fold_gelu(const f16* __restrict__ h_t, f16* __restrict__ imgG)
{
    const int r  = blockIdx.x;        // 0..65
    const int bc = blockIdx.y;        // bp*40 + cch
    const int bp  = bc / 40;
    const int cch = bc % 40;
    const int c = threadIdx.x;
    if (c >= 114) return;
    float outv = 0.f;
    if (r >= 3 && r < 63 && c >= 3 && c < 111) {
        const int qr = r / 3, rm = r % 3;
        const int qc = c / 3, cm = c % 3;
        int kis[3], ohs[3], nr = 0;
        int kjs[3], ows[3], nc = 0;
#pragma unroll
        for (int t = 0; t < 3; ++t) {
            const int ki = rm + 3 * t, oh = qr - t;
            if (ki < 7 && oh >= 0 && oh < 20) { kis[nr] = ki; ohs[nr] = oh; ++nr; }
            const int kj = cm + 3 * t, ow = qc - t;
            if (kj < 7 && ow >= 0 && ow < 36) { kjs[nc] = kj; ows[nc] = ow; ++nc; }
        }
        float sum = 0.f;
        for (int a = 0; a < nr; ++a)
            for (int b = 0; b < nc; ++b) {
                const int n = cch * 49 + kis[a] * 7 + kjs[b];
                const int token = bp * 720 + ohs[a] * 36 + ows[b];
                sum += (float)h_t[n * 11520 + token];
            }
        const float xv = sum / (float)(nr * nc);
        outv = 0.5f * xv * (1.f + erff(xv * 0.70710678118654752f));
    }
    imgG[(bc * 66 + r) * 114 + c] = (f16)outv;
}

// ---------------------------------------------------------------------------
// unfold: stage one channel image (15 KB) in LDS, then gather + write g16.
// Block per (bp,cch); cch>=36 blocks also zero tail cols [1960,2048).
// ---------------------------------------------------------------------------
__global__ __launch_bounds__(256) void unfold_lds(
    const f16* __restrict__ imgG, f16* __restrict__ g16)
{
    __shared__ f16 ch[7524];
    const int bc = blockIdx.x;        // 0..639
    const int bp = bc / 40, cch = bc % 40;
    const float* src = (const float*)(imgG + bc * 7524);
    float* dst = (float*)ch;
    for (int i = threadIdx.x; i < 3762; i += 256) dst[i] = src[i];
    __syncthreads();
    const int tokbase = bp * 720;
    const int colbase = cch * 49;
    for (int flat = threadIdx.x; flat < 35280; flat += 256) {
        const int l = flat / 49, k = flat - l * 49;
        const int oh = l / 36, ow = l - oh * 36;
        const int ki = k / 7,  kj = k - ki * 7;
        g16[(tokbase + l) * 2048 + colbase + k] =
            ch[(oh * 3 + ki) * 114 + ow * 3 + kj];
    }
    if (cch >= 36) {
        const int cb = 1960 + (cch - 36) * 22;   // 4 blocks x 22 cols = 88
        for (int flat = threadIdx.x; flat < 720 * 22; flat += 256) {
            const int l = flat / 22, k = flat - l * 22;
            g16[(tokbase + l) * 2048 + cb + k] = (f16)0.f;
        }
    }
}

// ---------------------------------------------------------------------------
// prep: fuses x->f16 convert + both weight transposes (one dispatch).
// blocks [0,5760): cvt; [5760,6784): W1 -> W1t; [6784,7808): W2 -> W2t
// ---------------------------------------------------------------------------
__global__ __launch_bounds__(256) void prep(
    const float* __restrict__ x, f16* __restrict__ xh,
    const float* __restrict__ W1, f16* __restrict__ W1t,
    const float* __restrict__ W2, f16* __restrict__ W2t)
{
    __shared__ float tile[32][33];
    const int b = blockIdx.x, t = threadIdx.x;
    if (b < 5760) {
        const int i = b * 256 + t;     // < 1474560 float4s
        const float4 v = ((const float4*)x)[i];
        half4 o;
        o[0] = (f16)v.x; o[1] = (f16)v.y; o[2] = (f16)v.z; o[3] = (f16)v.w;
        ((half4*)xh)[i] = o;
        return;
    }
    const float* src; f16* dst; int R, C, Rp, Cp, bx, by;
    if (b < 6784) {
        const int local = b - 5760;    // grid (16,64)
        bx = local & 15; by = local >> 4;
        src = W1; dst = W1t; R = 512; C = 1960; Rp = 512; Cp = 2048;
    } else {
        const int local = b - 6784;    // grid (64,16)
        bx = local & 63; by = local >> 6;
        src = W2; dst = W2t; R = 1960; C = 512; Rp = 2048; Cp = 512;
    }
    const int r0 = bx * 32, c0 = by * 32;
    const int tx = t & 31, ty = t >> 5;
#pragma unroll
    for (int i = 0; i < 32; i += 8) {
        const int r = r0 + ty + i, c = c0 + tx;
        tile[ty + i][tx] = (r < R && c < C) ? src[r * C + c] : 0.f;
    }
    __syncthreads();
#pragma unroll
    for (int i = 0; i < 32; i += 8) {
        const int c = c0 + ty + i, r = r0 + tx;
        if (c < Cp && r < Rp) dst[c * Rp + r] = (f16)tile[tx][ty + i];
    }
}

// ---------------------------------------------------------------------------
extern "C" void kernel_launch(void* const* d_in, const int* in_sizes, int n_in,
                              void* d_out, int out_size, void* d_ws, size_t ws_size,
                              hipStream_t stream)
{
    const float* x  = (const float*)d_in[0];
    const float* W1 = (const float*)d_in[1];
    const float* b1 = (const float*)d_in[2];
    const float* W2 = (const float*)d_in[3];
    const float* b2 = (const float*)d_in[4];

    char* ws = (char*)d_ws;
    f16* xh   = (f16*)(ws);                                       // 11,796,480 B
    f16* W1t  = (f16*)(ws + 11796480);                            //  2,097,152 B
    f16* W2t  = (f16*)(ws + 11796480 + 2097152);                  //  2,097,152 B
    f16* hbuf = (f16*)(ws + 11796480 + 2 * 2097152);              // 47,185,920 B (h_t, then g16)
    f16* imgG = (f16*)(ws + 11796480 + 2 * 2097152 + 47185920);   //  9,630,720 B

    // fused convert + transposes
    prep<<<dim3(7808), dim3(256), 0, stream>>>(x, xh, W1, W1t, W2, W2t);
    // GEMM1 (2-stage pipelined): h_t = W1t @ xh^T + b1(row)
    gemm1<<<dim3(1536), dim3(256), 0, stream>>>(W1t, xh, b1, hbuf);
    // fold + normalize + GELU -> f16 image
    fold_gelu<<<dim3(66, 640), dim3(128), 0, stream>>>(hbuf, imgG);
    // unfold via LDS staging -> g16[token][2048] (overwrites hbuf; zero tail)
    unfold_lds<<<dim3(640), dim3(256), 0, stream>>>(imgG, hbuf);
    // GEMM2 (3-stage pipeline, XCD-swizzled): out = g16 @ W2t^T + b2
    gemm2<<<dim3(384), dim3(256), 0, stream>>>(hbuf, W2t, b2, (float*)d_out);
}